// Round 13
// baseline (1903.088 us; speedup 1.0000x reference)
//
#include <hip/hip_runtime.h>

// Problem constants
#define B_ 32
#define S_ 64
#define T_ 65
#define D_ 256
#define HE 512    // encoder hidden
#define HD 1024   // decoder hidden
#define VV 32000

typedef __attribute__((ext_vector_type(8))) short bf16x8;
typedef __attribute__((ext_vector_type(4))) float f32x4;
typedef __attribute__((ext_vector_type(4))) unsigned int u32x4;

__device__ inline unsigned short f2bf(float f) {
  unsigned int u = __float_as_uint(f);
  u += 0x7FFFu + ((u >> 16) & 1u);   // RNE
  return (unsigned short)(u >> 16);
}
__device__ inline float sigmf(float x) { return 1.0f / (1.0f + __expf(-x)); }

#define MFMA16(a,b,c) __builtin_amdgcn_mfma_f32_16x16x32_bf16((a),(b),(c),0,0,0)

// ---------------- epoch sync primitives (line-granular coherent) -----------
// Shared data uses device-scope (sc1, IF-coherent) accesses; no cache-wide
// maintenance. sig_epoch: drain this block's stores, then publish epoch.
// waitg / waitg2: poll slot arrays until epochs reached (needs <= 0 skip).
#define SLOT_STRIDE 32   // 32 ints = 128B per slot
__device__ inline void sig_epoch(int* slot, int e) {
  asm volatile("s_waitcnt vmcnt(0)" ::: "memory");
  __syncthreads();
  if (threadIdx.x == 0)
    __hip_atomic_store(slot, e, __ATOMIC_RELAXED, __HIP_MEMORY_SCOPE_AGENT);
}
__device__ inline void waitg(int* slots, int cnt, int need) {
  const int tid = threadIdx.x;
  if (need > 0 && tid < cnt) {
    while (__hip_atomic_load(&slots[tid * SLOT_STRIDE], __ATOMIC_RELAXED,
                             __HIP_MEMORY_SCOPE_AGENT) < need)
      __builtin_amdgcn_s_sleep(2);
  }
  __syncthreads();
}
__device__ inline void waitg2(int* sA, int nA, int* sB, int nB) {
  const int tid = threadIdx.x;
  if (tid < 64) {
    if (nA > 0) {
      while (__hip_atomic_load(&sA[tid * SLOT_STRIDE], __ATOMIC_RELAXED,
                               __HIP_MEMORY_SCOPE_AGENT) < nA)
        __builtin_amdgcn_s_sleep(2);
    }
  } else if (tid < 128) {
    if (nB > 0) {
      while (__hip_atomic_load(&sB[(tid - 64) * SLOT_STRIDE], __ATOMIC_RELAXED,
                               __HIP_MEMORY_SCOPE_AGENT) < nB)
        __builtin_amdgcn_s_sleep(2);
    }
  }
  __syncthreads();
}
// Legacy all-poll barrier (encoders).
__device__ inline void gbar_all(int* slots, int nblk, int e, int bid) {
  asm volatile("s_waitcnt vmcnt(0)" ::: "memory");
  __syncthreads();
  const int tid = threadIdx.x;
  if (tid == 0)
    __hip_atomic_store(&slots[bid * SLOT_STRIDE], e, __ATOMIC_RELAXED,
                       __HIP_MEMORY_SCOPE_AGENT);
  if (tid < nblk) {
    while (__hip_atomic_load(&slots[tid * SLOT_STRIDE], __ATOMIC_RELAXED,
                             __HIP_MEMORY_SCOPE_AGENT) < e)
      __builtin_amdgcn_s_sleep(2);
  }
  __syncthreads();
}

// ---- device-scope (sc1, IF-coherent) 16B load -----------------------------
__device__ inline u32x4 ld16_sc(const void* p) {
  u32x4 r;
  asm volatile("global_load_dwordx4 %0, %1, off sc1"
               : "=v"(r)
               : "v"((unsigned long long)p)
               : "memory");
  return r;
}

// ---- async global->LDS, 16B per lane (linear dest = base + lane*16) -------
__device__ inline void gl_lds16(const short* g, short* l) {
  __builtin_amdgcn_global_load_lds(
      (const __attribute__((address_space(1))) short*)g,
      (__attribute__((address_space(3))) short*)l, 16, 0, 0);
}

// XOR-swizzle of 16B chunks within a row by (row&7) — LDS bank spread.
__device__ inline int swz(int row, int col, int LD) {
  return row * LD + ((((col >> 3) ^ (row & 7)) << 3) | (col & 7));
}
// Single-source staging: all chunks in flight at once.
template <int LD>
__device__ inline void stage1a(short* lds, const short* src) {
  const int tid = threadIdx.x;
  constexpr int NPT = LD / 64;
  u32x4 t[NPT];
#pragma unroll
  for (int i = 0; i < NPT; i++)
    t[i] = ld16_sc(src + ((size_t)(i * 256 + tid)) * 8);
  asm volatile("s_waitcnt vmcnt(0)" ::: "memory");
  __builtin_amdgcn_sched_barrier(0);
#pragma unroll
  for (int i = 0; i < NPT; i++) {
    int o = (i * 256 + tid) * 8;
    *(u32x4*)(lds + swz(o / LD, o % LD, LD)) = t[i];
  }
}

// ---------------- mask dtype detection + dense int8 mask -------------------
__device__ inline int mask_dtype(const unsigned char* m) {
  unsigned b0 = m[0], b1 = m[1], b2 = m[2], b3 = m[3], b4 = m[4];
  if (b0 == 1 && b1 == 1) return 0;
  if (b0 == 1) {
    if (b4 == 1) return 1;
    if (b4 == 0 && m[8] == 1) return 2;
    return 1;
  }
  if (b0 == 0x80 && b1 == 0x3F) return 4;
  if (b0 == 0x00 && b1 == 0x3C) return 5;
  if (b2 == 0x80 && b3 == 0x3F) return 3;
  return 1;
}
__device__ inline int mask_val(const unsigned char* m, int dt, int i) {
  switch (dt) {
    case 0: return m[i] != 0;
    case 1: return ((const int*)m)[i] != 0;
    case 2: return ((const long long*)m)[i] != 0;
    case 3: return ((const float*)m)[i] != 0.0f;
    default: return ((const unsigned short*)m)[i] != 0;
  }
}
__global__ void k_masks(const unsigned char* msrc, const unsigned char* mtgt,
                        signed char* o_src, signed char* o_tgt) {
  const unsigned char* m = blockIdx.x ? mtgt : msrc;
  signed char* o = blockIdx.x ? o_tgt : o_src;
  int n = blockIdx.x ? (B_ * T_) : (B_ * S_);
  int dt = mask_dtype(m);
  for (int i = threadIdx.x; i < n; i += blockDim.x)
    o[i] = (signed char)mask_val(m, dt, i);
}

// ---------------- fp32 -> bf16 weight conversion (13 tensors) --------------
struct CvtJobs {
  const float* src[13];
  short* dst[13];
  int n4[13];
};
__global__ __launch_bounds__(256) void k_convert(CvtJobs jb) {
  int j = blockIdx.y;
  const float4* s = (const float4*)jb.src[j];
  ushort4* d = (ushort4*)jb.dst[j];
  int n4 = jb.n4[j];
  for (int i = blockIdx.x * blockDim.x + threadIdx.x; i < n4;
       i += gridDim.x * blockDim.x) {
    float4 v = s[i];
    ushort4 o;
    o.x = f2bf(v.x); o.y = f2bf(v.y); o.z = f2bf(v.z); o.w = f2bf(v.w);
    d[i] = o;
  }
}

// ---------------- embedding gather -> bf16 ----------------------------------
__global__ __launch_bounds__(256) void k_gather(const int* sids, const int* tids,
                                                const float* es, const float* et,
                                                short* Xs, short* Xt) {
  int job = blockIdx.y;
  int rows = job ? (B_ * T_) : (B_ * S_);
  const int* ids = job ? tids : sids;
  const float* emb = job ? et : es;
  ushort4* X = (ushort4*)(job ? Xt : Xs);
  int total = rows * (D_ / 4);
  for (int i = blockIdx.x * blockDim.x + threadIdx.x; i < total;
       i += gridDim.x * blockDim.x) {
    int row = i >> 6;
    int c4 = i & 63;
    long id = ids[row];
    float4 v = ((const float4*)(emb + id * (long)D_))[c4];
    ushort4 o;
    o.x = f2bf(v.x); o.y = f2bf(v.y); o.z = f2bf(v.z); o.w = f2bf(v.w);
    X[(long)row * 64 + c4] = o;
  }
}

// ---------------- MFMA GEMM: Cf[M,N] = A[Mp,K](bf16) · B[N,K]^T + bias ------
__global__ __launch_bounds__(256) void k_gemm(const short* __restrict__ A,
                                              const short* __restrict__ Bw,
                                              const float* __restrict__ bias,
                                              float* __restrict__ Cf,
                                              int M_out, int N, int K) {
  __shared__ short As[128 * 32];
  __shared__ short Bs[128 * 32];
  const int tid = threadIdx.x;
  const int wave = tid >> 6, lane = tid & 63;
  const int wm = wave >> 1, wn = wave & 1;
  const int r16 = lane & 15, kb = lane >> 4;
  const long m0 = (long)blockIdx.y * 128;
  const long n0 = (long)blockIdx.x * 128;

  const int c0 = wave * 128 + lane, c1 = c0 + 64;
  const int rA0 = c0 >> 2, kA0 = (c0 & 3) * 8;
  const int rA1 = c1 >> 2, kA1 = (c1 & 3) * 8;
  short* lA0 = As + (size_t)(wave * 128) * 8;
  short* lA1 = As + (size_t)(wave * 128 + 64) * 8;
  short* lB0 = Bs + (size_t)(wave * 128) * 8;
  short* lB1 = Bs + (size_t)(wave * 128 + 64) * 8;

  f32x4 acc[4][4];
#pragma unroll
  for (int i = 0; i < 4; i++)
#pragma unroll
    for (int j = 0; j < 4; j++) acc[i][j] = (f32x4){0.f, 0.f, 0.f, 0.f};

  for (int kt = 0; kt < K; kt += 32) {
    __syncthreads();
    gl_lds16(A + (m0 + rA0) * K + kt + kA0, lA0);
    gl_lds16(A + (m0 + rA1) * K + kt + kA1, lA1);
    gl_lds16(Bw + (n0 + rA0) * K + kt + kA0, lB0);
    gl_lds16(Bw + (n0 + rA1) * K + kt + kA1, lB1);
    __syncthreads();
    bf16x8 av[4], bv[4];
#pragma unroll
    for (int i = 0; i < 4; i++)
      av[i] = *(const bf16x8*)(As + (wm * 64 + i * 16 + r16) * 32 + kb * 8);
#pragma unroll
    for (int j = 0; j < 4; j++)
      bv[j] = *(const bf16x8*)(Bs + (wn * 64 + j * 16 + r16) * 32 + kb * 8);
#pragma unroll
    for (int i = 0; i < 4; i++)
#pragma unroll
      for (int j = 0; j < 4; j++) acc[i][j] = MFMA16(av[i], bv[j], acc[i][j]);
  }
#pragma unroll
  for (int j = 0; j < 4; j++) {
    long gc = n0 + wn * 64 + j * 16 + r16;
    float bb = bias ? bias[gc] : 0.f;
#pragma unroll
    for (int i = 0; i < 4; i++) {
      long gr0 = m0 + wm * 64 + i * 16 + kb * 4;
#pragma unroll
      for (int r = 0; r < 4; r++) {
        long gr = gr0 + r;
        if (gr < M_out) Cf[gr * N + gc] = acc[i][j][r] + bb;
      }
    }
  }
}

// ---------------- persistent encoder layer (64 steps, both dirs) -----------
__global__ __launch_bounds__(256) void k_enc_persist(
    const short* __restrict__ Wf, const short* __restrict__ Wb_,
    short* __restrict__ H, const float* __restrict__ Pf,
    const float* __restrict__ Pb, short* __restrict__ Outb, int outLD,
    int outOffDir, float* __restrict__ Cfin,
    const signed char* __restrict__ msk, int* slots) {
  const int dir = blockIdx.y;
  const short* W = dir ? Wb_ : Wf;
  const float* P = dir ? Pb : Pf;
  int* slotsD = slots + dir * 32 * SLOT_STRIDE;
  const int q = threadIdx.x >> 6, lane = threadIdx.x & 63;
  const int r16 = lane & 15, kb = lane >> 4;
  const int n = q * HE + blockIdx.x * 16 + r16;
  const short* wr = W + (size_t)n * HE;
  const int bb = threadIdx.x >> 3;
  const int cp = threadIdx.x & 7;
  const int j0 = blockIdx.x * 16 + 2 * cp;
  __shared__ short h_lds[32 * HE];
  __shared__ float g_lds[4][2][16][17];
  float creg0 = 0.f, creg1 = 0.f;

  for (int s = 0; s < S_; ++s) {
    const int t = dir ? (S_ - 1 - s) : s;
    const int rp = s & 1;
    const short* Ar = H + ((size_t)rp * 2 + dir) * (B_ * HE);
    short* Hw = H + ((size_t)(rp ^ 1) * 2 + dir) * (B_ * HE);

    const float* pr = P + (size_t)(bb * S_ + t) * (4 * HE);
    float2 pv[4];
#pragma unroll
    for (int g = 0; g < 4; g++) pv[g] = *(const float2*)(pr + g * HE + j0);
    bool valid = msk[bb * S_ + t] != 0;

    __syncthreads();
    stage1a<HE>(h_lds, Ar);
    __syncthreads();

    f32x4 acc0 = (f32x4){0.f, 0.f, 0.f, 0.f};
    f32x4 acc1 = (f32x4){0.f, 0.f, 0.f, 0.f};
#pragma unroll 8
    for (int k = kb * 8; k < HE; k += 32) {
      bf16x8 bv = *(const bf16x8*)(wr + k);
      bf16x8 a0 = *(const bf16x8*)(h_lds + swz(r16, k, HE));
      bf16x8 a1 = *(const bf16x8*)(h_lds + swz(16 + r16, k, HE));
      acc0 = MFMA16(a0, bv, acc0);
      acc1 = MFMA16(a1, bv, acc1);
    }
#pragma unroll
    for (int r = 0; r < 4; r++) {
      g_lds[q][0][kb * 4 + r][r16] = acc0[r];
      g_lds[q][1][kb * 4 + r][r16] = acc1[r];
    }
    __syncthreads();
    {
      const int mt = bb >> 4, br = bb & 15;
      float h2v[2];
#pragma unroll
      for (int cc = 0; cc < 2; ++cc) {
        float g0 = g_lds[0][mt][br][2 * cp + cc] + (cc ? pv[0].y : pv[0].x);
        float g1 = g_lds[1][mt][br][2 * cp + cc] + (cc ? pv[1].y : pv[1].x);
        float g2 = g_lds[2][mt][br][2 * cp + cc] + (cc ? pv[2].y : pv[2].x);
        float g3 = g_lds[3][mt][br][2 * cp + cc] + (cc ? pv[3].y : pv[3].x);
        float co = cc ? creg1 : creg0;
        float c2 = sigmf(g1) * co + sigmf(g0) * tanhf(g2);
        float h2 = sigmf(g3) * tanhf(c2);
        if (valid) { if (cc) creg1 = c2; else creg0 = c2; }
        h2v[cc] = h2;
      }
      unsigned short o0 = valid ? f2bf(h2v[0])
                                : (unsigned short)h_lds[swz(bb, j0, HE)];
      unsigned short o1 = valid ? f2bf(h2v[1])
                                : (unsigned short)h_lds[swz(bb, j0 + 1, HE)];
      unsigned int hv = (unsigned int)o0 | ((unsigned int)o1 << 16);
      __hip_atomic_store((unsigned int*)(Hw + bb * HE + j0), hv,
                         __ATOMIC_RELAXED, __HIP_MEMORY_SCOPE_AGENT);
      if (Outb) {
        unsigned int ov = valid ? hv : 0u;
        *(unsigned int*)(Outb + (size_t)(bb * S_ + t) * outLD +
                         outOffDir * dir + j0) = ov;
      }
    }
    if (s < S_ - 1) gbar_all(slotsD, 32, s + 1, blockIdx.x);
  }
  Cfin[(size_t)(dir * B_ + bb) * HE + j0] = creg0;
  Cfin[(size_t)(dir * B_ + bb) * HE + j0 + 1] = creg1;
}

// ---------------- persistent decoder: DECOUPLED roles ----------------------
// Role0 phase k (k=0..T_-1): L0(t=k); reads H1[k%4] writes H1[(k+1)%4].
//   waits: e0 >= k (own), e1 >= k-3 (ring-4 overwrite guard). Runs ahead.
// Role1 phase k (k=1..T_): L1(t=k-1); reads H1[k%4] (prefetched) + H2 2-ring.
//   waits: e1 >= k-1 (own); prefetches next h1 after signaling (e0 >= k+1,
//   usually already satisfied since role0 runs ahead).
__global__ __launch_bounds__(256) void k_dec_persist(
    const short* __restrict__ dU0b, const short* __restrict__ dW1b,
    const short* __restrict__ dU1b, short* __restrict__ H1,
    short* __restrict__ H2, const float* __restrict__ Q0,
    const float* __restrict__ db1f, const float* __restrict__ dC1i,
    const float* __restrict__ dC2i, short* __restrict__ douts,
    const signed char* __restrict__ msk, int* slots) {
  int* e0 = slots;                      // 64 slots
  int* e1 = slots + 64 * SLOT_STRIDE;   // 64 slots
  const int role = blockIdx.y;
  const int bx = blockIdx.x;
  const int q = threadIdx.x >> 6, lane = threadIdx.x & 63;
  const int r16 = lane & 15, kb = lane >> 4;
  const int n = q * HD + bx * 16 + r16;
  const int bb = threadIdx.x >> 3;
  const int cp = threadIdx.x & 7;
  const int j0 = bx * 16 + 2 * cp;
  __shared__ short h_lds1[32 * HD];
  __shared__ short h_lds2[32 * HD];
  __shared__ float g_lds[4][2][16][17];
  const float* Ci = role ? dC2i : dC1i;
  float creg0 = Ci[(size_t)bb * HD + j0];
  float creg1 = Ci[(size_t)bb * HD + j0 + 1];

  if (role == 0) {
    const short* w0 = dU0b + (size_t)n * HD;
    for (int k = 0; k < T_; ++k) {
      waitg2(e0, k, e1, k - 3);
      const int t = k;
      const short* Ar = H1 + (size_t)(k % 4) * (B_ * HD);
      short* Hw = H1 + (size_t)((k + 1) % 4) * (B_ * HD);
      const float* pr = Q0 + (size_t)(bb * T_ + t) * (4 * HD);
      float2 pv[4];
#pragma unroll
      for (int g = 0; g < 4; g++) pv[g] = *(const float2*)(pr + g * HD + j0);
      bool valid = msk[bb * T_ + t] != 0;
      stage1a<HD>(h_lds1, Ar);
      __syncthreads();
      f32x4 acc0 = (f32x4){0.f, 0.f, 0.f, 0.f};
      f32x4 acc1 = (f32x4){0.f, 0.f, 0.f, 0.f};
#pragma unroll 8
      for (int kk = kb * 8; kk < HD; kk += 32) {
        bf16x8 bv = *(const bf16x8*)(w0 + kk);
        bf16x8 a0 = *(const bf16x8*)(h_lds1 + swz(r16, kk, HD));
        bf16x8 a1 = *(const bf16x8*)(h_lds1 + swz(16 + r16, kk, HD));
        acc0 = MFMA16(a0, bv, acc0);
        acc1 = MFMA16(a1, bv, acc1);
      }
#pragma unroll
      for (int r = 0; r < 4; r++) {
        g_lds[q][0][kb * 4 + r][r16] = acc0[r];
        g_lds[q][1][kb * 4 + r][r16] = acc1[r];
      }
      __syncthreads();
      {
        const int mt = bb >> 4, br = bb & 15;
        float h2v[2];
#pragma unroll
        for (int cc = 0; cc < 2; ++cc) {
          float g0 = g_lds[0][mt][br][2 * cp + cc] + (cc ? pv[0].y : pv[0].x);
          float g1 = g_lds[1][mt][br][2 * cp + cc] + (cc ? pv[1].y : pv[1].x);
          float g2 = g_lds[2][mt][br][2 * cp + cc] + (cc ? pv[2].y : pv[2].x);
          float g3 = g_lds[3][mt][br][2 * cp + cc] + (cc ? pv[3].y : pv[3].x);
          float co = cc ? creg1 : creg0;
          float c2 = sigmf(g1) * co + sigmf(g0) * tanhf(g2);
          float h2 = sigmf(g3) * tanhf(c2);
          if (valid) { if (cc) creg1 = c2; else creg0 = c2; }
          h2v[cc] = h2;
        }
        unsigned short o0 = valid ? f2bf(h2v[0])
                                  : (unsigned short)h_lds1[swz(bb, j0, HD)];
        unsigned short o1 = valid ? f2bf(h2v[1])
                                  : (unsigned short)h_lds1[swz(bb, j0 + 1, HD)];
        unsigned int hv = (unsigned int)o0 | ((unsigned int)o1 << 16);
        __hip_atomic_store((unsigned int*)(Hw + bb * HD + j0), hv,
                           __ATOMIC_RELAXED, __HIP_MEMORY_SCOPE_AGENT);
      }
      sig_epoch(&e0[bx * SLOT_STRIDE], k + 1);
    }
  } else {
    const short* w1 = dW1b + (size_t)n * HD;
    const short* w2 = dU1b + (size_t)n * HD;
    float2 pvB[4];                        // bias: loop-invariant
#pragma unroll
    for (int g = 0; g < 4; g++) pvB[g] = *(const float2*)(db1f + g * HD + j0);
    // initial h1 stage for phase 1 (H1[1], written by role0 phase 0)
    waitg(e0, 64, 1);
    stage1a<HD>(h_lds1, H1 + (size_t)1 * (B_ * HD));
    for (int k = 1; k <= T_; ++k) {
      waitg(e1, 64, k - 1);
      const int t = k - 1;
      bool valid = msk[bb * T_ + t] != 0;
      stage1a<HD>(h_lds2, H2 + (size_t)((k + 1) & 1) * (B_ * HD));
      __syncthreads();
      short* Hw = H2 + (size_t)(k & 1) * (B_ * HD);
      f32x4 acc0 = (f32x4){0.f, 0.f, 0.f, 0.f};
      f32x4 acc1 = (f32x4){0.f, 0.f, 0.f, 0.f};
#pragma unroll 4
      for (int kk = kb * 8; kk < HD; kk += 32) {
        bf16x8 bv1 = *(const bf16x8*)(w1 + kk);
        bf16x8 a0 = *(const bf16x8*)(h_lds1 + swz(r16, kk, HD));
        bf16x8 a1 = *(const bf16x8*)(h_lds1 + swz(16 + r16, kk, HD));
        acc0 = MFMA16(a0, bv1, acc0);
        acc1 = MFMA16(a1, bv1, acc1);
        bf16x8 bv2 = *(const bf16x8*)(w2 + kk);
        bf16x8 b0 = *(const bf16x8*)(h_lds2 + swz(r16, kk, HD));
        bf16x8 b1 = *(const bf16x8*)(h_lds2 + swz(16 + r16, kk, HD));
        acc0 = MFMA16(b0, bv2, acc0);
        acc1 = MFMA16(b1, bv2, acc1);
      }
#pragma unroll
      for (int r = 0; r < 4; r++) {
        g_lds[q][0][kb * 4 + r][r16] = acc0[r];
        g_lds[q][1][kb * 4 + r][r16] = acc1[r];
      }
      __syncthreads();
      {
        const int mt = bb >> 4, br = bb & 15;
        float h2v[2];
#pragma unroll
        for (int cc = 0; cc < 2; ++cc) {
          float g0 = g_lds[0][mt][br][2 * cp + cc] + (cc ? pvB[0].y : pvB[0].x);
          float g1 = g_lds[1][mt][br][2 * cp + cc] + (cc ? pvB[1].y : pvB[1].x);
          float g2 = g_lds[2][mt][br][2 * cp + cc] + (cc ? pvB[2].y : pvB[2].x);
          float g3 = g_lds[3][mt][br][2 * cp + cc] + (cc ? pvB[3].y : pvB[3].x);
          float co = cc ? creg1 : creg0;
          float c2 = sigmf(g1) * co + sigmf(g0) * tanhf(g2);
          float h2 = sigmf(g3) * tanhf(c2);
          if (valid) { if (cc) creg1 = c2; else creg0 = c2; }
          h2v[cc] = h2;
        }
        unsigned short o0 = valid ? f2bf(h2v[0])
                                  : (unsigned short)h_lds2[swz(bb, j0, HD)];
        unsigned short o1 = valid ? f2bf(h2v[1])
                                  : (unsigned short)h_lds2[swz(bb, j0 + 1, HD)];
        unsigned int hv = (unsigned int)o0 | ((unsigned int)o1 << 16);
        __hip_atomic_store((unsigned int*)(Hw + bb * HD + j0), hv,
                           __ATOMIC_RELAXED, __HIP_MEMORY_SCOPE_AGENT);
        *(unsigned int*)(douts + (size_t)(bb * T_ + t) * HD + j0) =
            valid ? hv : 0u;
      }
      sig_epoch(&e1[bx * SLOT_STRIDE], k);
      if (k < T_) {
        // prefetch next h1 (role0 runs ahead; wait usually instant)
        waitg(e0, 64, k + 1);
        stage1a<HD>(h_lds1, H1 + (size_t)((k + 1) % 4) * (B_ * HD));
      }
    }
  }
}

// ---------------- decoder state init from encoder finals --------------------
__global__ __launch_bounds__(256) void k_decinit(const short* h0, const float* c0,
                                                 const short* h1, const float* c1f,
                                                 short* dh1, float* dc1,
                                                 short* dh2, float* dc2) {
  int i = blockIdx.x * 256 + threadIdx.x;
  if (i < B_ * HD) {
    int b = i >> 10, nn = i & 1023, d = nn >> 9, jj = nn & 511;
    int src = (d * B_ + b) * HE + jj;
    dh1[i] = h0[src];
    dc1[i] = c0[src];
    dh2[i] = h1[src];
    dc2[i] = c1f[src];
  }
}

// ---------------------------------------------------------------------------
extern "C" void kernel_launch(void* const* d_in, const int* in_sizes, int n_in,
                              void* d_out, int out_size, void* d_ws, size_t ws_size,
                              hipStream_t stream) {
  const int* src = (const int*)d_in[0];
  const unsigned char* msrc = (const unsigned char*)d_in[1];
  const int* tgt = (const int*)d_in[2];
  const unsigned char* mtgt = (const unsigned char*)d_in[3];
  const float* emb_s = (const float*)d_in[4];
  const float* emb_t = (const float*)d_in[5];
  const float* eW0f = (const float*)d_in[6];
  const float* eU0f = (const float*)d_in[7];
  const float* eb0f = (const float*)d_in[8];
  const float* eW0b = (const float*)d_in[9];
  const float* eU0b = (const float*)d_in[10];
  const float* eb0b = (const float*)d_in[11];
  const float* eW1f = (const float*)d_in[12];
  const float* eU1f = (const float*)d_in[13];
  const float* eb1f = (const float*)d_in[14];
  const float* eW1b = (const float*)d_in[15];
  const float* eU1b = (const float*)d_in[16];
  const float* eb1b = (const float*)d_in[17];
  const float* dW0 = (const float*)d_in[18];
  const float* dU0 = (const float*)d_in[19];
  const float* db0 = (const float*)d_in[20];
  const float* dW1 = (const float*)d_in[21];
  const float* dU1 = (const float*)d_in[22];
  const float* db1 = (const float*)d_in[23];
  const float* wW = (const float*)d_in[24];
  const float* wb = (const float*)d_in[25];
  (void)n_in; (void)in_sizes; (void)out_size; (void)ws_size;

  // ---- d_ws: douts + wW_b (both live during the final GEMM). ~70 MB ----
  short* douts = (short*)d_ws;                       // [2176][1024] bf16
  short* wW_b = (short*)((char*)d_ws + (size_t)2176 * 1024 * 2);  // [VV][1024]

  // ---- d_out scratch (266 MB): dead before the final GEMM ----
  char* po = (char*)d_out;
  size_t off = 0;
  auto alloc = [&](size_t bytes) -> char* {
    char* p = po + off;
    off += (bytes + 255) & ~(size_t)255;
    return p;
  };
  const size_t szW[12] = {
      (size_t)2048 * 256 * 2,  (size_t)2048 * 512 * 2,
      (size_t)2048 * 256 * 2,  (size_t)2048 * 512 * 2,
      (size_t)2048 * 1024 * 2, (size_t)2048 * 512 * 2,
      (size_t)2048 * 1024 * 2, (size_t)2048 * 512 * 2,
      (size_t)4096 * 256 * 2,  (size_t)4096 * 1024 * 2,
      (size_t)4096 * 1024 * 2, (size_t)4096 * 1024 * 2};
  short* Wb[12];
  for (int i = 0; i < 12; i++) Wb[i] = (short*)alloc(szW[i]);
  short* eW0f_b = Wb[0], *eU0f_b = Wb[1], *eW0b_b = Wb[2], *eU0b_b = Wb[3];
  short* eW1f_b = Wb[4], *eU1f_b = Wb[5], *eW1b_b = Wb[6], *eU1b_b = Wb[7];
  short* dW0_b = Wb[8], *dU0_b = Wb[9], *dW1_b = Wb[10], *dU1_b = Wb[11];
  short* Xs_b = (short*)alloc((size_t)2048 * 256 * 2);
  short* Xt_b = (short*)alloc((size_t)2176 * 256 * 2);
  short* X1_b = (short*)alloc((size_t)2048 * 1024 * 2);
  char* uni = alloc((size_t)2176 * 4096 * 4);        // P0 | P1 | Q0 (aliased)
  float* P0f = (float*)uni;
  float* P0b = P0f + (size_t)2048 * 2048;
  float* P1f = (float*)uni;
  float* P1b = P1f + (size_t)2048 * 2048;
  float* Q0 = (float*)uni;
  // zero block: barrier/epoch slots + encoder h states
  char* zero_begin = po + off;
  int* slots_e0 = (int*)alloc(2 * 32 * SLOT_STRIDE * 4);
  int* slots_e1 = (int*)alloc(2 * 32 * SLOT_STRIDE * 4);
  int* slots_d = (int*)alloc(128 * SLOT_STRIDE * 4);
  short* encH0 = (short*)alloc((size_t)2 * 2 * B_ * HE * 2);
  short* encH1 = (short*)alloc((size_t)2 * 2 * B_ * HE * 2);
  size_t zero_bytes = (size_t)((po + off) - zero_begin);
  float* Cfin0 = (float*)alloc((size_t)2 * B_ * HE * 4);
  float* Cfin1 = (float*)alloc((size_t)2 * B_ * HE * 4);
  short* dH1 = (short*)alloc((size_t)4 * B_ * HD * 2);   // ring-4 [slot][B][HD]
  short* dH2 = (short*)alloc((size_t)2 * B_ * HD * 2);   // 2-ring
  float* dC1f = (float*)alloc((size_t)B_ * HD * 4);
  float* dC2f = (float*)alloc((size_t)B_ * HD * 4);
  signed char* msk_s = (signed char*)alloc(B_ * S_);
  signed char* msk_t = (signed char*)alloc(B_ * T_);

  // 1) zero: douts, slots+enc states; masks; weight cvt (incl wW); gathers
  (void)hipMemsetAsync(douts, 0, (size_t)2176 * 1024 * 2, stream);
  (void)hipMemsetAsync(zero_begin, 0, zero_bytes, stream);
  k_masks<<<dim3(2), dim3(256), 0, stream>>>(msrc, mtgt, msk_s, msk_t);
  CvtJobs jb;
  const float* srcs[13] = {eW0f, eU0f, eW0b, eU0b, eW1f, eU1f,
                           eW1b, eU1b, dW0, dU0, dW1, dU1, wW};
  short* dsts[13] = {Wb[0], Wb[1], Wb[2], Wb[3], Wb[4], Wb[5],
                     Wb[6], Wb[7], Wb[8], Wb[9], Wb[10], Wb[11], wW_b};
  int ns[13] = {2048 * 256, 2048 * 512, 2048 * 256, 2048 * 512,
                2048 * 1024, 2048 * 512, 2048 * 1024, 2048 * 512,
                4096 * 256, 4096 * 1024, 4096 * 1024, 4096 * 1024, VV * 1024};
  for (int i = 0; i < 13; i++) { jb.src[i] = srcs[i]; jb.dst[i] = dsts[i]; jb.n4[i] = ns[i] / 4; }
  k_convert<<<dim3(1024, 13), 256, 0, stream>>>(jb);
  k_gather<<<dim3(544, 2), 256, 0, stream>>>(src, tgt, emb_s, emb_t, Xs_b, Xt_b);

  // 2) encoder layer-0 input projections (fp32 out, bias folded)
  k_gemm<<<dim3(16, 16), 256, 0, stream>>>(Xs_b, eW0f_b, eb0f, P0f,
                                           2048, 2048, 256);
  k_gemm<<<dim3(16, 16), 256, 0, stream>>>(Xs_b, eW0b_b, eb0b, P0b,
                                           2048, 2048, 256);

  // 3) encoder layer 0 persistent -> X1, Cfin0
  k_enc_persist<<<dim3(32, 2), 256, 0, stream>>>(
      eU0f_b, eU0b_b, encH0, P0f, P0b, X1_b, 1024, 512, Cfin0, msk_s, slots_e0);

  // 4) encoder layer-1 input projections (alias P0; P0 dead)
  k_gemm<<<dim3(16, 16), 256, 0, stream>>>(X1_b, eW1f_b, eb1f, P1f,
                                           2048, 2048, 1024);
  k_gemm<<<dim3(16, 16), 256, 0, stream>>>(X1_b, eW1b_b, eb1b, P1b,
                                           2048, 2048, 1024);

  // 5) encoder layer 1 persistent (finals only) -> Cfin1
  k_enc_persist<<<dim3(32, 2), 256, 0, stream>>>(
      eU1f_b, eU1b_b, encH1, P1f, P1b, (short*)nullptr, 0, 0, Cfin1, msk_s,
      slots_e1);

  // 6) decoder init from encoder finals (H1 slot 0, H2 slot 0)
  k_decinit<<<dim3(128), 256, 0, stream>>>(encH0, Cfin0, encH1, Cfin1,
                                           dH1, dC1f, dH2, dC2f);

  // 7) decoder layer-0 input projection (alias P1; P1 dead; db0 folded)
  k_gemm<<<dim3(32, 17), 256, 0, stream>>>(Xt_b, dW0_b, db0, Q0,
                                           2176, 4096, 256);

  // 8) decoder persistent: decoupled roles, epoch sync
  k_dec_persist<<<dim3(64, 2), 256, 0, stream>>>(
      dU0_b, dW1_b, dU1_b, dH1, dH2, Q0, db1, dC1f, dC2f, douts, msk_t,
      slots_d);

  // 9) logits = douts(bf16) @ wW_b^T(bf16) + wb -> fp32 d_out
  k_gemm<<<dim3(250, 17), 256, 0, stream>>>(douts, wW_b, wb, (float*)d_out,
                                            B_ * T_, VV, 1024);
}

// Round 16
// 1886.336 us; speedup vs baseline: 1.0089x; 1.0089x over previous
//
#include <hip/hip_runtime.h>

// Problem constants
#define B_ 32
#define S_ 64
#define T_ 65
#define D_ 256
#define HE 512    // encoder hidden
#define HD 1024   // decoder hidden
#define VV 32000

typedef __attribute__((ext_vector_type(8))) short bf16x8;
typedef __attribute__((ext_vector_type(4))) float f32x4;
typedef __attribute__((ext_vector_type(4))) unsigned int u32x4;

__device__ inline unsigned short f2bf(float f) {
  unsigned int u = __float_as_uint(f);
  u += 0x7FFFu + ((u >> 16) & 1u);   // RNE
  return (unsigned short)(u >> 16);
}
__device__ inline float sigmf(float x) { return 1.0f / (1.0f + __expf(-x)); }

#define MFMA16(a,b,c) __builtin_amdgcn_mfma_f32_16x16x32_bf16((a),(b),(c),0,0,0)

// ---------------- epoch sync primitives (line-granular coherent) -----------
// Shared data uses device-scope (sc1, IF-coherent) accesses; no cache-wide
// maintenance. sig_epoch: drain this block's stores, then publish epoch.
// waitg / waitg2: poll slot arrays until epochs reached (needs <= 0 skip).
#define SLOT_STRIDE 32   // 32 ints = 128B per slot
__device__ inline void sig_epoch(int* slot, int e) {
  asm volatile("s_waitcnt vmcnt(0)" ::: "memory");
  __syncthreads();
  if (threadIdx.x == 0)
    __hip_atomic_store(slot, e, __ATOMIC_RELAXED, __HIP_MEMORY_SCOPE_AGENT);
}
__device__ inline void waitg(int* slots, int cnt, int need) {
  const int tid = threadIdx.x;
  if (need > 0 && tid < cnt) {
    while (__hip_atomic_load(&slots[tid * SLOT_STRIDE], __ATOMIC_RELAXED,
                             __HIP_MEMORY_SCOPE_AGENT) < need)
      __builtin_amdgcn_s_sleep(2);
  }
  __syncthreads();
}
__device__ inline void waitg2(int* sA, int nA, int* sB, int nB) {
  const int tid = threadIdx.x;
  if (tid < 64) {
    if (nA > 0) {
      while (__hip_atomic_load(&sA[tid * SLOT_STRIDE], __ATOMIC_RELAXED,
                               __HIP_MEMORY_SCOPE_AGENT) < nA)
        __builtin_amdgcn_s_sleep(2);
    }
  } else if (tid < 128) {
    if (nB > 0) {
      while (__hip_atomic_load(&sB[(tid - 64) * SLOT_STRIDE], __ATOMIC_RELAXED,
                               __HIP_MEMORY_SCOPE_AGENT) < nB)
        __builtin_amdgcn_s_sleep(2);
    }
  }
  __syncthreads();
}
// Legacy all-poll barrier (encoders).
__device__ inline void gbar_all(int* slots, int nblk, int e, int bid) {
  asm volatile("s_waitcnt vmcnt(0)" ::: "memory");
  __syncthreads();
  const int tid = threadIdx.x;
  if (tid == 0)
    __hip_atomic_store(&slots[bid * SLOT_STRIDE], e, __ATOMIC_RELAXED,
                       __HIP_MEMORY_SCOPE_AGENT);
  if (tid < nblk) {
    while (__hip_atomic_load(&slots[tid * SLOT_STRIDE], __ATOMIC_RELAXED,
                             __HIP_MEMORY_SCOPE_AGENT) < e)
      __builtin_amdgcn_s_sleep(2);
  }
  __syncthreads();
}

// ---- device-scope (sc1, IF-coherent) 16B load -----------------------------
__device__ inline u32x4 ld16_sc(const void* p) {
  u32x4 r;
  asm volatile("global_load_dwordx4 %0, %1, off sc1"
               : "=v"(r)
               : "v"((unsigned long long)p)
               : "memory");
  return r;
}

// ---- async global->LDS, 16B per lane (linear dest = base + lane*16) -------
__device__ inline void gl_lds16(const short* g, short* l) {
  __builtin_amdgcn_global_load_lds(
      (const __attribute__((address_space(1))) short*)g,
      (__attribute__((address_space(3))) short*)l, 16, 0, 0);
}

// XOR-swizzle of 16B chunks within a row by (row&7) — LDS bank spread.
__device__ inline int swz(int row, int col, int LD) {
  return row * LD + ((((col >> 3) ^ (row & 7)) << 3) | (col & 7));
}
// Single-source staging: all chunks in flight at once.
template <int LD>
__device__ inline void stage1a(short* lds, const short* src) {
  const int tid = threadIdx.x;
  constexpr int NPT = LD / 64;
  u32x4 t[NPT];
#pragma unroll
  for (int i = 0; i < NPT; i++)
    t[i] = ld16_sc(src + ((size_t)(i * 256 + tid)) * 8);
  asm volatile("s_waitcnt vmcnt(0)" ::: "memory");
  __builtin_amdgcn_sched_barrier(0);
#pragma unroll
  for (int i = 0; i < NPT; i++) {
    int o = (i * 256 + tid) * 8;
    *(u32x4*)(lds + swz(o / LD, o % LD, LD)) = t[i];
  }
}

// ---------------- mask dtype detection + dense int8 mask -------------------
__device__ inline int mask_dtype(const unsigned char* m) {
  unsigned b0 = m[0], b1 = m[1], b2 = m[2], b3 = m[3], b4 = m[4];
  if (b0 == 1 && b1 == 1) return 0;
  if (b0 == 1) {
    if (b4 == 1) return 1;
    if (b4 == 0 && m[8] == 1) return 2;
    return 1;
  }
  if (b0 == 0x80 && b1 == 0x3F) return 4;
  if (b0 == 0x00 && b1 == 0x3C) return 5;
  if (b2 == 0x80 && b3 == 0x3F) return 3;
  return 1;
}
__device__ inline int mask_val(const unsigned char* m, int dt, int i) {
  switch (dt) {
    case 0: return m[i] != 0;
    case 1: return ((const int*)m)[i] != 0;
    case 2: return ((const long long*)m)[i] != 0;
    case 3: return ((const float*)m)[i] != 0.0f;
    default: return ((const unsigned short*)m)[i] != 0;
  }
}
__global__ void k_masks(const unsigned char* msrc, const unsigned char* mtgt,
                        signed char* o_src, signed char* o_tgt) {
  const unsigned char* m = blockIdx.x ? mtgt : msrc;
  signed char* o = blockIdx.x ? o_tgt : o_src;
  int n = blockIdx.x ? (B_ * T_) : (B_ * S_);
  int dt = mask_dtype(m);
  for (int i = threadIdx.x; i < n; i += blockDim.x)
    o[i] = (signed char)mask_val(m, dt, i);
}

// ---------------- fp32 -> bf16 weight conversion (13 tensors) --------------
struct CvtJobs {
  const float* src[13];
  short* dst[13];
  int n4[13];
};
__global__ __launch_bounds__(256) void k_convert(CvtJobs jb) {
  int j = blockIdx.y;
  const float4* s = (const float4*)jb.src[j];
  ushort4* d = (ushort4*)jb.dst[j];
  int n4 = jb.n4[j];
  for (int i = blockIdx.x * blockDim.x + threadIdx.x; i < n4;
       i += gridDim.x * blockDim.x) {
    float4 v = s[i];
    ushort4 o;
    o.x = f2bf(v.x); o.y = f2bf(v.y); o.z = f2bf(v.z); o.w = f2bf(v.w);
    d[i] = o;
  }
}

// ---------------- embedding gather -> bf16 ----------------------------------
__global__ __launch_bounds__(256) void k_gather(const int* sids, const int* tids,
                                                const float* es, const float* et,
                                                short* Xs, short* Xt) {
  int job = blockIdx.y;
  int rows = job ? (B_ * T_) : (B_ * S_);
  const int* ids = job ? tids : sids;
  const float* emb = job ? et : es;
  ushort4* X = (ushort4*)(job ? Xt : Xs);
  int total = rows * (D_ / 4);
  for (int i = blockIdx.x * blockDim.x + threadIdx.x; i < total;
       i += gridDim.x * blockDim.x) {
    int row = i >> 6;
    int c4 = i & 63;
    long id = ids[row];
    float4 v = ((const float4*)(emb + id * (long)D_))[c4];
    ushort4 o;
    o.x = f2bf(v.x); o.y = f2bf(v.y); o.z = f2bf(v.z); o.w = f2bf(v.w);
    X[(long)row * 64 + c4] = o;
  }
}

// ---------------- MFMA GEMM: Cf[M,N] = A[Mp,K](bf16) · B[N,K]^T + bias ------
__global__ __launch_bounds__(256) void k_gemm(const short* __restrict__ A,
                                              const short* __restrict__ Bw,
                                              const float* __restrict__ bias,
                                              float* __restrict__ Cf,
                                              int M_out, int N, int K) {
  __shared__ short As[128 * 32];
  __shared__ short Bs[128 * 32];
  const int tid = threadIdx.x;
  const int wave = tid >> 6, lane = tid & 63;
  const int wm = wave >> 1, wn = wave & 1;
  const int r16 = lane & 15, kb = lane >> 4;
  const long m0 = (long)blockIdx.y * 128;
  const long n0 = (long)blockIdx.x * 128;

  const int c0 = wave * 128 + lane, c1 = c0 + 64;
  const int rA0 = c0 >> 2, kA0 = (c0 & 3) * 8;
  const int rA1 = c1 >> 2, kA1 = (c1 & 3) * 8;
  short* lA0 = As + (size_t)(wave * 128) * 8;
  short* lA1 = As + (size_t)(wave * 128 + 64) * 8;
  short* lB0 = Bs + (size_t)(wave * 128) * 8;
  short* lB1 = Bs + (size_t)(wave * 128 + 64) * 8;

  f32x4 acc[4][4];
#pragma unroll
  for (int i = 0; i < 4; i++)
#pragma unroll
    for (int j = 0; j < 4; j++) acc[i][j] = (f32x4){0.f, 0.f, 0.f, 0.f};

  for (int kt = 0; kt < K; kt += 32) {
    __syncthreads();
    gl_lds16(A + (m0 + rA0) * K + kt + kA0, lA0);
    gl_lds16(A + (m0 + rA1) * K + kt + kA1, lA1);
    gl_lds16(Bw + (n0 + rA0) * K + kt + kA0, lB0);
    gl_lds16(Bw + (n0 + rA1) * K + kt + kA1, lB1);
    __syncthreads();
    bf16x8 av[4], bv[4];
#pragma unroll
    for (int i = 0; i < 4; i++)
      av[i] = *(const bf16x8*)(As + (wm * 64 + i * 16 + r16) * 32 + kb * 8);
#pragma unroll
    for (int j = 0; j < 4; j++)
      bv[j] = *(const bf16x8*)(Bs + (wn * 64 + j * 16 + r16) * 32 + kb * 8);
#pragma unroll
    for (int i = 0; i < 4; i++)
#pragma unroll
      for (int j = 0; j < 4; j++) acc[i][j] = MFMA16(av[i], bv[j], acc[i][j]);
  }
#pragma unroll
  for (int j = 0; j < 4; j++) {
    long gc = n0 + wn * 64 + j * 16 + r16;
    float bb = bias ? bias[gc] : 0.f;
#pragma unroll
    for (int i = 0; i < 4; i++) {
      long gr0 = m0 + wm * 64 + i * 16 + kb * 4;
#pragma unroll
      for (int r = 0; r < 4; r++) {
        long gr = gr0 + r;
        if (gr < M_out) Cf[gr * N + gc] = acc[i][j][r] + bb;
      }
    }
  }
}

// ---------------- persistent encoder layer (64 steps, both dirs) -----------
__global__ __launch_bounds__(256) void k_enc_persist(
    const short* __restrict__ Wf, const short* __restrict__ Wb_,
    short* __restrict__ H, const float* __restrict__ Pf,
    const float* __restrict__ Pb, short* __restrict__ Outb, int outLD,
    int outOffDir, float* __restrict__ Cfin,
    const signed char* __restrict__ msk, int* slots) {
  const int dir = blockIdx.y;
  const short* W = dir ? Wb_ : Wf;
  const float* P = dir ? Pb : Pf;
  int* slotsD = slots + dir * 32 * SLOT_STRIDE;
  const int q = threadIdx.x >> 6, lane = threadIdx.x & 63;
  const int r16 = lane & 15, kb = lane >> 4;
  const int n = q * HE + blockIdx.x * 16 + r16;
  const short* wr = W + (size_t)n * HE;
  const int bb = threadIdx.x >> 3;
  const int cp = threadIdx.x & 7;
  const int j0 = blockIdx.x * 16 + 2 * cp;
  __shared__ short h_lds[32 * HE];
  __shared__ float g_lds[4][2][16][17];
  float creg0 = 0.f, creg1 = 0.f;

  for (int s = 0; s < S_; ++s) {
    const int t = dir ? (S_ - 1 - s) : s;
    const int rp = s & 1;
    const short* Ar = H + ((size_t)rp * 2 + dir) * (B_ * HE);
    short* Hw = H + ((size_t)(rp ^ 1) * 2 + dir) * (B_ * HE);

    const float* pr = P + (size_t)(bb * S_ + t) * (4 * HE);
    float2 pv[4];
#pragma unroll
    for (int g = 0; g < 4; g++) pv[g] = *(const float2*)(pr + g * HE + j0);
    bool valid = msk[bb * S_ + t] != 0;

    __syncthreads();
    stage1a<HE>(h_lds, Ar);
    __syncthreads();

    f32x4 acc0 = (f32x4){0.f, 0.f, 0.f, 0.f};
    f32x4 acc1 = (f32x4){0.f, 0.f, 0.f, 0.f};
#pragma unroll 8
    for (int k = kb * 8; k < HE; k += 32) {
      bf16x8 bv = *(const bf16x8*)(wr + k);
      bf16x8 a0 = *(const bf16x8*)(h_lds + swz(r16, k, HE));
      bf16x8 a1 = *(const bf16x8*)(h_lds + swz(16 + r16, k, HE));
      acc0 = MFMA16(a0, bv, acc0);
      acc1 = MFMA16(a1, bv, acc1);
    }
#pragma unroll
    for (int r = 0; r < 4; r++) {
      g_lds[q][0][kb * 4 + r][r16] = acc0[r];
      g_lds[q][1][kb * 4 + r][r16] = acc1[r];
    }
    __syncthreads();
    {
      const int mt = bb >> 4, br = bb & 15;
      float h2v[2];
#pragma unroll
      for (int cc = 0; cc < 2; ++cc) {
        float g0 = g_lds[0][mt][br][2 * cp + cc] + (cc ? pv[0].y : pv[0].x);
        float g1 = g_lds[1][mt][br][2 * cp + cc] + (cc ? pv[1].y : pv[1].x);
        float g2 = g_lds[2][mt][br][2 * cp + cc] + (cc ? pv[2].y : pv[2].x);
        float g3 = g_lds[3][mt][br][2 * cp + cc] + (cc ? pv[3].y : pv[3].x);
        float co = cc ? creg1 : creg0;
        float c2 = sigmf(g1) * co + sigmf(g0) * tanhf(g2);
        float h2 = sigmf(g3) * tanhf(c2);
        if (valid) { if (cc) creg1 = c2; else creg0 = c2; }
        h2v[cc] = h2;
      }
      unsigned short o0 = valid ? f2bf(h2v[0])
                                : (unsigned short)h_lds[swz(bb, j0, HE)];
      unsigned short o1 = valid ? f2bf(h2v[1])
                                : (unsigned short)h_lds[swz(bb, j0 + 1, HE)];
      unsigned int hv = (unsigned int)o0 | ((unsigned int)o1 << 16);
      __hip_atomic_store((unsigned int*)(Hw + bb * HE + j0), hv,
                         __ATOMIC_RELAXED, __HIP_MEMORY_SCOPE_AGENT);
      if (Outb) {
        unsigned int ov = valid ? hv : 0u;
        *(unsigned int*)(Outb + (size_t)(bb * S_ + t) * outLD +
                         outOffDir * dir + j0) = ov;
      }
    }
    if (s < S_ - 1) gbar_all(slotsD, 32, s + 1, blockIdx.x);
  }
  Cfin[(size_t)(dir * B_ + bb) * HE + j0] = creg0;
  Cfin[(size_t)(dir * B_ + bb) * HE + j0 + 1] = creg1;
}

// ---------------- persistent decoder: DECOUPLED roles ----------------------
// Role0 phase k (k=0..T_-1): L0(t=k); reads H1[k%4] writes H1[(k+1)%4].
//   waits: e0 >= k (own), e1 >= k-3 (ring-4 overwrite guard). Runs ahead.
// Role1 phase k (k=1..T_): L1(t=k-1); reads H1[k%4] (prefetched) + H2 2-ring.
//   waits: e1 >= k-1 (own); prefetches next h1 after signaling.
__global__ __launch_bounds__(256) void k_dec_persist(
    const short* __restrict__ dU0b, const short* __restrict__ dW1b,
    const short* __restrict__ dU1b, short* __restrict__ H1,
    short* __restrict__ H2, const float* __restrict__ Q0,
    const float* __restrict__ db1f, const float* __restrict__ dC1i,
    const float* __restrict__ dC2i, short* __restrict__ douts,
    const signed char* __restrict__ msk, int* slots) {
  int* e0 = slots;                      // 64 slots
  int* e1 = slots + 64 * SLOT_STRIDE;   // 64 slots
  const int role = blockIdx.y;
  const int bx = blockIdx.x;
  const int q = threadIdx.x >> 6, lane = threadIdx.x & 63;
  const int r16 = lane & 15, kb = lane >> 4;
  const int n = q * HD + bx * 16 + r16;
  const int bb = threadIdx.x >> 3;
  const int cp = threadIdx.x & 7;
  const int j0 = bx * 16 + 2 * cp;
  __shared__ short h_lds1[32 * HD];
  __shared__ short h_lds2[32 * HD];
  __shared__ float g_lds[4][2][16][17];
  const float* Ci = role ? dC2i : dC1i;
  float creg0 = Ci[(size_t)bb * HD + j0];
  float creg1 = Ci[(size_t)bb * HD + j0 + 1];

  if (role == 0) {
    const short* w0 = dU0b + (size_t)n * HD;
    for (int k = 0; k < T_; ++k) {
      waitg2(e0, k, e1, k - 3);
      const int t = k;
      const short* Ar = H1 + (size_t)(k % 4) * (B_ * HD);
      short* Hw = H1 + (size_t)((k + 1) % 4) * (B_ * HD);
      const float* pr = Q0 + (size_t)(bb * T_ + t) * (4 * HD);
      float2 pv[4];
#pragma unroll
      for (int g = 0; g < 4; g++) pv[g] = *(const float2*)(pr + g * HD + j0);
      bool valid = msk[bb * T_ + t] != 0;
      stage1a<HD>(h_lds1, Ar);
      __syncthreads();
      f32x4 acc0 = (f32x4){0.f, 0.f, 0.f, 0.f};
      f32x4 acc1 = (f32x4){0.f, 0.f, 0.f, 0.f};
#pragma unroll 8
      for (int kk = kb * 8; kk < HD; kk += 32) {
        bf16x8 bv = *(const bf16x8*)(w0 + kk);
        bf16x8 a0 = *(const bf16x8*)(h_lds1 + swz(r16, kk, HD));
        bf16x8 a1 = *(const bf16x8*)(h_lds1 + swz(16 + r16, kk, HD));
        acc0 = MFMA16(a0, bv, acc0);
        acc1 = MFMA16(a1, bv, acc1);
      }
#pragma unroll
      for (int r = 0; r < 4; r++) {
        g_lds[q][0][kb * 4 + r][r16] = acc0[r];
        g_lds[q][1][kb * 4 + r][r16] = acc1[r];
      }
      __syncthreads();
      {
        const int mt = bb >> 4, br = bb & 15;
        float h2v[2];
#pragma unroll
        for (int cc = 0; cc < 2; ++cc) {
          float g0 = g_lds[0][mt][br][2 * cp + cc] + (cc ? pv[0].y : pv[0].x);
          float g1 = g_lds[1][mt][br][2 * cp + cc] + (cc ? pv[1].y : pv[1].x);
          float g2 = g_lds[2][mt][br][2 * cp + cc] + (cc ? pv[2].y : pv[2].x);
          float g3 = g_lds[3][mt][br][2 * cp + cc] + (cc ? pv[3].y : pv[3].x);
          float co = cc ? creg1 : creg0;
          float c2 = sigmf(g1) * co + sigmf(g0) * tanhf(g2);
          float h2 = sigmf(g3) * tanhf(c2);
          if (valid) { if (cc) creg1 = c2; else creg0 = c2; }
          h2v[cc] = h2;
        }
        unsigned short o0 = valid ? f2bf(h2v[0])
                                  : (unsigned short)h_lds1[swz(bb, j0, HD)];
        unsigned short o1 = valid ? f2bf(h2v[1])
                                  : (unsigned short)h_lds1[swz(bb, j0 + 1, HD)];
        unsigned int hv = (unsigned int)o0 | ((unsigned int)o1 << 16);
        __hip_atomic_store((unsigned int*)(Hw + bb * HD + j0), hv,
                           __ATOMIC_RELAXED, __HIP_MEMORY_SCOPE_AGENT);
      }
      sig_epoch(&e0[bx * SLOT_STRIDE], k + 1);
    }
  } else {
    const short* w1 = dW1b + (size_t)n * HD;
    const short* w2 = dU1b + (size_t)n * HD;
    float2 pvB[4];                        // bias: loop-invariant
#pragma unroll
    for (int g = 0; g < 4; g++) pvB[g] = *(const float2*)(db1f + g * HD + j0);
    // initial h1 stage for phase 1 (H1[1], written by role0 phase 0)
    waitg(e0, 64, 1);
    stage1a<HD>(h_lds1, H1 + (size_t)1 * (B_ * HD));
    for (int k = 1; k <= T_; ++k) {
      waitg(e1, 64, k - 1);
      const int t = k - 1;
      bool valid = msk[bb * T_ + t] != 0;
      stage1a<HD>(h_lds2, H2 + (size_t)((k + 1) & 1) * (B_ * HD));
      __syncthreads();
      short* Hw = H2 + (size_t)(k & 1) * (B_ * HD);
      f32x4 acc0 = (f32x4){0.f, 0.f, 0.f, 0.f};
      f32x4 acc1 = (f32x4){0.f, 0.f, 0.f, 0.f};
#pragma unroll 4
      for (int kk = kb * 8; kk < HD; kk += 32) {
        bf16x8 bv1 = *(const bf16x8*)(w1 + kk);
        bf16x8 a0 = *(const bf16x8*)(h_lds1 + swz(r16, kk, HD));
        bf16x8 a1 = *(const bf16x8*)(h_lds1 + swz(16 + r16, kk, HD));
        acc0 = MFMA16(a0, bv1, acc0);
        acc1 = MFMA16(a1, bv1, acc1);
        bf16x8 bv2 = *(const bf16x8*)(w2 + kk);
        bf16x8 b0 = *(const bf16x8*)(h_lds2 + swz(r16, kk, HD));
        bf16x8 b1 = *(const bf16x8*)(h_lds2 + swz(16 + r16, kk, HD));
        acc0 = MFMA16(b0, bv2, acc0);
        acc1 = MFMA16(b1, bv2, acc1);
      }
#pragma unroll
      for (int r = 0; r < 4; r++) {
        g_lds[q][0][kb * 4 + r][r16] = acc0[r];
        g_lds[q][1][kb * 4 + r][r16] = acc1[r];
      }
      __syncthreads();
      {
        const int mt = bb >> 4, br = bb & 15;
        float h2v[2];
#pragma unroll
        for (int cc = 0; cc < 2; ++cc) {
          float g0 = g_lds[0][mt][br][2 * cp + cc] + (cc ? pvB[0].y : pvB[0].x);
          float g1 = g_lds[1][mt][br][2 * cp + cc] + (cc ? pvB[1].y : pvB[1].x);
          float g2 = g_lds[2][mt][br][2 * cp + cc] + (cc ? pvB[2].y : pvB[2].x);
          float g3 = g_lds[3][mt][br][2 * cp + cc] + (cc ? pvB[3].y : pvB[3].x);
          float co = cc ? creg1 : creg0;
          float c2 = sigmf(g1) * co + sigmf(g0) * tanhf(g2);
          float h2 = sigmf(g3) * tanhf(c2);
          if (valid) { if (cc) creg1 = c2; else creg0 = c2; }
          h2v[cc] = h2;
        }
        unsigned short o0 = valid ? f2bf(h2v[0])
                                  : (unsigned short)h_lds2[swz(bb, j0, HD)];
        unsigned short o1 = valid ? f2bf(h2v[1])
                                  : (unsigned short)h_lds2[swz(bb, j0 + 1, HD)];
        unsigned int hv = (unsigned int)o0 | ((unsigned int)o1 << 16);
        __hip_atomic_store((unsigned int*)(Hw + bb * HD + j0), hv,
                           __ATOMIC_RELAXED, __HIP_MEMORY_SCOPE_AGENT);
        *(unsigned int*)(douts + (size_t)(bb * T_ + t) * HD + j0) =
            valid ? hv : 0u;
      }
      sig_epoch(&e1[bx * SLOT_STRIDE], k);
      if (k < T_) {
        // prefetch next h1 (role0 runs ahead; wait usually instant)
        waitg(e0, 64, k + 1);
        stage1a<HD>(h_lds1, H1 + (size_t)((k + 1) % 4) * (B_ * HD));
      }
    }
  }
}

// ---------------- decoder state init from encoder finals --------------------
__global__ __launch_bounds__(256) void k_decinit(const short* h0, const float* c0,
                                                 const short* h1, const float* c1f,
                                                 short* dh1, float* dc1,
                                                 short* dh2, float* dc2) {
  int i = blockIdx.x * 256 + threadIdx.x;
  if (i < B_ * HD) {
    int b = i >> 10, nn = i & 1023, d = nn >> 9, jj = nn & 511;
    int src = (d * B_ + b) * HE + jj;
    dh1[i] = h0[src];
    dc1[i] = c0[src];
    dh2[i] = h1[src];
    dc2[i] = c1f[src];
  }
}

// ---------------------------------------------------------------------------
extern "C" void kernel_launch(void* const* d_in, const int* in_sizes, int n_in,
                              void* d_out, int out_size, void* d_ws, size_t ws_size,
                              hipStream_t stream) {
  const int* src = (const int*)d_in[0];
  const unsigned char* msrc = (const unsigned char*)d_in[1];
  const int* tgt = (const int*)d_in[2];
  const unsigned char* mtgt = (const unsigned char*)d_in[3];
  const float* emb_s = (const float*)d_in[4];
  const float* emb_t = (const float*)d_in[5];
  const float* eW0f = (const float*)d_in[6];
  const float* eU0f = (const float*)d_in[7];
  const float* eb0f = (const float*)d_in[8];
  const float* eW0b = (const float*)d_in[9];
  const float* eU0b = (const float*)d_in[10];
  const float* eb0b = (const float*)d_in[11];
  const float* eW1f = (const float*)d_in[12];
  const float* eU1f = (const float*)d_in[13];
  const float* eb1f = (const float*)d_in[14];
  const float* eW1b = (const float*)d_in[15];
  const float* eU1b = (const float*)d_in[16];
  const float* eb1b = (const float*)d_in[17];
  const float* dW0 = (const float*)d_in[18];
  const float* dU0 = (const float*)d_in[19];
  const float* db0 = (const float*)d_in[20];
  const float* dW1 = (const float*)d_in[21];
  const float* dU1 = (const float*)d_in[22];
  const float* db1 = (const float*)d_in[23];
  const float* wW = (const float*)d_in[24];
  const float* wb = (const float*)d_in[25];
  (void)n_in; (void)in_sizes; (void)out_size; (void)ws_size;

  // ---- d_ws: douts + wW_b (both live during the final GEMM). ~70 MB ----
  short* douts = (short*)d_ws;                       // [2176][1024] bf16
  short* wW_b = (short*)((char*)d_ws + (size_t)2176 * 1024 * 2);  // [VV][1024]

  // ---- d_out scratch (266 MB): dead before the final GEMM ----
  char* po = (char*)d_out;
  size_t off = 0;
  auto alloc = [&](size_t bytes) -> char* {
    char* p = po + off;
    off += (bytes + 255) & ~(size_t)255;
    return p;
  };
  const size_t szW[12] = {
      (size_t)2048 * 256 * 2,  (size_t)2048 * 512 * 2,
      (size_t)2048 * 256 * 2,  (size_t)2048 * 512 * 2,
      (size_t)2048 * 1024 * 2, (size_t)2048 * 512 * 2,
      (size_t)2048 * 1024 * 2, (size_t)2048 * 512 * 2,
      (size_t)4096 * 256 * 2,  (size_t)4096 * 1024 * 2,
      (size_t)4096 * 1024 * 2, (size_t)4096 * 1024 * 2};
  short* Wb[12];
  for (int i = 0; i < 12; i++) Wb[i] = (short*)alloc(szW[i]);
  short* eW0f_b = Wb[0], *eU0f_b = Wb[1], *eW0b_b = Wb[2], *eU0b_b = Wb[3];
  short* eW1f_b = Wb[4], *eU1f_b = Wb[5], *eW1b_b = Wb[6], *eU1b_b = Wb[7];
  short* dW0_b = Wb[8], *dU0_b = Wb[9], *dW1_b = Wb[10], *dU1_b = Wb[11];
  short* Xs_b = (short*)alloc((size_t)2048 * 256 * 2);
  short* Xt_b = (short*)alloc((size_t)2176 * 256 * 2);
  short* X1_b = (short*)alloc((size_t)2048 * 1024 * 2);
  char* uni = alloc((size_t)2176 * 4096 * 4);        // P0 | P1 | Q0 (aliased)
  float* P0f = (float*)uni;
  float* P0b = P0f + (size_t)2048 * 2048;
  float* P1f = (float*)uni;
  float* P1b = P1f + (size_t)2048 * 2048;
  float* Q0 = (float*)uni;
  // zero block: barrier/epoch slots + encoder h states
  char* zero_begin = po + off;
  int* slots_e0 = (int*)alloc(2 * 32 * SLOT_STRIDE * 4);
  int* slots_e1 = (int*)alloc(2 * 32 * SLOT_STRIDE * 4);
  int* slots_d = (int*)alloc(128 * SLOT_STRIDE * 4);
  short* encH0 = (short*)alloc((size_t)2 * 2 * B_ * HE * 2);
  short* encH1 = (short*)alloc((size_t)2 * 2 * B_ * HE * 2);
  size_t zero_bytes = (size_t)((po + off) - zero_begin);
  float* Cfin0 = (float*)alloc((size_t)2 * B_ * HE * 4);
  float* Cfin1 = (float*)alloc((size_t)2 * B_ * HE * 4);
  short* dH1 = (short*)alloc((size_t)4 * B_ * HD * 2);   // ring-4 [slot][B][HD]
  short* dH2 = (short*)alloc((size_t)2 * B_ * HD * 2);   // 2-ring
  float* dC1f = (float*)alloc((size_t)B_ * HD * 4);
  float* dC2f = (float*)alloc((size_t)B_ * HD * 4);
  signed char* msk_s = (signed char*)alloc(B_ * S_);
  signed char* msk_t = (signed char*)alloc(B_ * T_);

  // 1) zero: douts, slots+enc states; masks; weight cvt (incl wW); gathers
  (void)hipMemsetAsync(douts, 0, (size_t)2176 * 1024 * 2, stream);
  (void)hipMemsetAsync(zero_begin, 0, zero_bytes, stream);
  k_masks<<<dim3(2), dim3(256), 0, stream>>>(msrc, mtgt, msk_s, msk_t);
  CvtJobs jb;
  const float* srcs[13] = {eW0f, eU0f, eW0b, eU0b, eW1f, eU1f,
                           eW1b, eU1b, dW0, dU0, dW1, dU1, wW};
  short* dsts[13] = {Wb[0], Wb[1], Wb[2], Wb[3], Wb[4], Wb[5],
                     Wb[6], Wb[7], Wb[8], Wb[9], Wb[10], Wb[11], wW_b};
  int ns[13] = {2048 * 256, 2048 * 512, 2048 * 256, 2048 * 512,
                2048 * 1024, 2048 * 512, 2048 * 1024, 2048 * 512,
                4096 * 256, 4096 * 1024, 4096 * 1024, 4096 * 1024, VV * 1024};
  for (int i = 0; i < 13; i++) { jb.src[i] = srcs[i]; jb.dst[i] = dsts[i]; jb.n4[i] = ns[i] / 4; }
  k_convert<<<dim3(1024, 13), 256, 0, stream>>>(jb);
  k_gather<<<dim3(544, 2), 256, 0, stream>>>(src, tgt, emb_s, emb_t, Xs_b, Xt_b);

  // 2) encoder layer-0 input projections (fp32 out, bias folded)
  k_gemm<<<dim3(16, 16), 256, 0, stream>>>(Xs_b, eW0f_b, eb0f, P0f,
                                           2048, 2048, 256);
  k_gemm<<<dim3(16, 16), 256, 0, stream>>>(Xs_b, eW0b_b, eb0b, P0b,
                                           2048, 2048, 256);

  // 3) encoder layer 0 persistent -> X1, Cfin0
  k_enc_persist<<<dim3(32, 2), 256, 0, stream>>>(
      eU0f_b, eU0b_b, encH0, P0f, P0b, X1_b, 1024, 512, Cfin0, msk_s, slots_e0);

  // 4) encoder layer-1 input projections (alias P0; P0 dead)
  k_gemm<<<dim3(16, 16), 256, 0, stream>>>(X1_b, eW1f_b, eb1f, P1f,
                                           2048, 2048, 1024);
  k_gemm<<<dim3(16, 16), 256, 0, stream>>>(X1_b, eW1b_b, eb1b, P1b,
                                           2048, 2048, 1024);

  // 5) encoder layer 1 persistent (finals only) -> Cfin1
  k_enc_persist<<<dim3(32, 2), 256, 0, stream>>>(
      eU1f_b, eU1b_b, encH1, P1f, P1b, (short*)nullptr, 0, 0, Cfin1, msk_s,
      slots_e1);

  // 6) decoder init from encoder finals (H1 slot 0, H2 slot 0)
  k_decinit<<<dim3(128), 256, 0, stream>>>(encH0, Cfin0, encH1, Cfin1,
                                           dH1, dC1f, dH2, dC2f);

  // 7) decoder layer-0 input projection (alias P1; P1 dead; db0 folded)
  k_gemm<<<dim3(32, 17), 256, 0, stream>>>(Xt_b, dW0_b, db0, Q0,
                                           2176, 4096, 256);

  // 8) decoder persistent: decoupled roles, epoch sync
  k_dec_persist<<<dim3(64, 2), 256, 0, stream>>>(
      dU0_b, dW1_b, dU1_b, dH1, dH2, Q0, db1, dC1f, dC2f, douts, msk_t,
      slots_d);

  // 9) logits = douts(bf16) @ wW_b^T(bf16) + wb -> fp32 d_out
  k_gemm<<<dim3(250, 17), 256, 0, stream>>>(douts, wW_b, wb, (float*)d_out,
                                            B_ * T_, VV, 1024);
}